// Round 2
// baseline (451.360 us; speedup 1.0000x reference)
//
#include <hip/hip_runtime.h>
#include <hip/hip_bf16.h>
#include <cmath>

// Problem constants
#define Bq   4
#define Lq   4096
#define Wq   2048
#define Hq   8
#define Mq   (Bq*Lq)        // 16384 rows
#define RCH  128            // rows per chunk (8 waves x 16 rows)
#define NCH  (Lq/RCH)       // 32 chunks per sequence

typedef __bf16 bf16;
typedef __attribute__((ext_vector_type(8))) __bf16 bf16x8;
typedef __attribute__((ext_vector_type(4))) float  f32x4;

// ---- workspace layout (bytes) ----
#define WS_WT    0                               // bf16 [2][8][256][256] = 2 MiB (n-major)
#define WS_C     (2*8*256*256*2)                 // float [2048]

// ---------------- K0: weight transpose/cast (LDS tiled) + c vector ----------------
__global__ __launch_bounds__(256) void prep2(const float* __restrict__ ig_w,
                                             const float* __restrict__ ag_w,
                                             const float* __restrict__ a_param,
                                             bf16* __restrict__ wt, float* __restrict__ c_arr) {
    __shared__ float t[64*65];
    int bid = blockIdx.x;                 // 256 blocks: [g:1][h:3][nt:2][kt:2]
    int kt = bid & 3, nt = (bid >> 2) & 3, h = (bid >> 4) & 7, g = bid >> 7;
    const float* src = g ? ag_w : ig_w;
    int rr = threadIdx.x >> 6, cc = threadIdx.x & 63;
#pragma unroll
    for (int p = 0; p < 16; p++) {
        int kl = p*4 + rr;
        t[kl*65 + cc] = src[h*65536 + (kt*64 + kl)*256 + nt*64 + cc];  // coalesced read
    }
    if (bid < 8) {
        float ap = a_param[bid*256 + threadIdx.x];
        c_arr[bid*256 + threadIdx.x] = 8.0f * log1pf(__expf(ap));      // 8*softplus
    }
    __syncthreads();
#pragma unroll
    for (int p = 0; p < 16; p++) {
        int nl = p*4 + rr;
        wt[((size_t)((g*8 + h)*256) + nt*64 + nl)*256 + kt*64 + cc] = (bf16)t[cc*65 + nl]; // coalesced write
    }
}

// ---------------- K1: fused persistent-chain RG-LRU (8-wave, RCH=128) ----------------
// 256 blocks = (stripe s:8)*(b:4)*(h:8), bid = s*32 + b*8 + h  -> bid%8==h: the 32
// blocks sharing an h-slab of x land on one XCD (round-robin) for L2 reuse.
// Each block owns 32 channels of one batch and walks 32 chunks of 128 rows,
// carrying h in LDS. Weights stay in VGPRs for the whole kernel.
// Phase structure per chunk (2 barriers):
//   A: MFMA(xs regs x resident weights) + stash raw x + issue next x loads + gates -> A/G/X LDS
//   B1; B: per-seg scan (16 segs x 8 rows) -> sg partials; B2; C: prefix + y store + carry.
// Single-buffered LDS is race-free: A/G/X written only in A (after prev B2),
// read only in B; sg written in B, read in C (next write is after next B1).
__global__ __launch_bounds__(512, 2) void rglru_fused(
    const float* __restrict__ x, const int* __restrict__ segpos,
    const float* __restrict__ prev_h,
    const bf16* __restrict__ wt, const float* __restrict__ igb,
    const float* __restrict__ agb, const float* __restrict__ c_arr,
    float* __restrict__ out)
{
    __shared__ float A_s[RCH*33];        // a            (stride 33)
    __shared__ float G_s[RCH*33];        // gx*mult
    __shared__ float X_s[RCH*36];        // raw x cols   (stride 36: b128-write friendly)
    __shared__ float sgA[512], sgH[512];
    __shared__ float hc[2][32];          // carry, ping-pong

    const int tid = threadIdx.x;
    const int bid = blockIdx.x;
    const int h = bid & 7, b = (bid >> 3) & 3, s = bid >> 5;
    const int lane = tid & 63, wv = tid >> 6;
    const int l16 = lane & 15, quad = lane >> 4;
    const int wcol0 = h*256 + s*32;      // global channel base of this block

    // ---- weight fragments: B[k][n] for n = wcol0 + ct*16 + l16, all 8 k-slices.
    bf16x8 wfx[2][8], wfa[2][8];
#pragma unroll
    for (int ct = 0; ct < 2; ct++) {
        const bf16* px = wt + ((size_t)(h*256 + s*32 + ct*16 + l16))*256 + quad*8;
        const bf16* pa = px + (size_t)Hq*256*256;
#pragma unroll
        for (int ks = 0; ks < 8; ks++) {
            wfx[ct][ks] = *(const bf16x8*)(px + (size_t)ks*32);
            wfa[ct][ks] = *(const bf16x8*)(pa + (size_t)ks*32);
        }
    }
    float bxv[2], bav[2], ccv[2];
#pragma unroll
    for (int ct = 0; ct < 2; ct++) {
        int wf = wcol0 + ct*16 + l16;
        bxv[ct] = igb[wf]; bav[ct] = agb[wf]; ccv[ct] = c_arr[wf];
    }
    if (tid < 32) hc[0][tid] = prev_h[b*Wq + wcol0 + tid];

    // per-lane x row pointer: lane (l16,quad) owns row wv*16+l16, k-cols quad*8..+7
    const float* xrow = x + ((size_t)b*Lq + wv*16 + l16)*Wq + h*256 + quad*8;

    // prefetch chunk 0 into registers (fragment-aligned: 2 float4 per k-slice)
    float4 xs[16];
#pragma unroll
    for (int ks = 0; ks < 8; ks++) {
        xs[2*ks]   = *(const float4*)(xrow + ks*32);
        xs[2*ks+1] = *(const float4*)(xrow + ks*32 + 4);
    }

    for (int c = 0; c < NCH; ++c) {
        // ---- phase A: GEMM against resident weights; stash raw x for our stripe
        f32x4 ax[2] = {{0.f,0.f,0.f,0.f},{0.f,0.f,0.f,0.f}};
        f32x4 aa[2] = {{0.f,0.f,0.f,0.f},{0.f,0.f,0.f,0.f}};
#pragma unroll
        for (int ks = 0; ks < 8; ks++) {
            float4 u0 = xs[2*ks], u1 = xs[2*ks+1];
            if (ks == s) {   // this k-slice IS our output channel stripe: stash raw x
                float* xp = &X_s[(wv*16 + l16)*36 + quad*8];
                *(float4*)xp = u0; *(float4*)(xp + 4) = u1;
            }
            bf16x8 af;
            af[0]=(bf16)u0.x; af[1]=(bf16)u0.y; af[2]=(bf16)u0.z; af[3]=(bf16)u0.w;
            af[4]=(bf16)u1.x; af[5]=(bf16)u1.y; af[6]=(bf16)u1.z; af[7]=(bf16)u1.w;
            ax[0] = __builtin_amdgcn_mfma_f32_16x16x32_bf16(af, wfx[0][ks], ax[0], 0,0,0);
            ax[1] = __builtin_amdgcn_mfma_f32_16x16x32_bf16(af, wfx[1][ks], ax[1], 0,0,0);
            aa[0] = __builtin_amdgcn_mfma_f32_16x16x32_bf16(af, wfa[0][ks], aa[0], 0,0,0);
            aa[1] = __builtin_amdgcn_mfma_f32_16x16x32_bf16(af, wfa[1][ks], aa[1], 0,0,0);
        }

        // ---- issue next chunk's x loads; gates+scan hide the latency
        {
            const float* xn_ = xrow + (size_t)((c < NCH-1) ? c+1 : c)*RCH*Wq;
#pragma unroll
            for (int ks = 0; ks < 8; ks++) {
                xs[2*ks]   = *(const float4*)(xn_ + ks*32);
                xs[2*ks+1] = *(const float4*)(xn_ + ks*32 + 4);
            }
        }

        // ---- gates: lane holds cols ct*16+l16, rows wv*16+quad*4+r
#pragma unroll
        for (int r = 0; r < 4; r++) {
            int grow = wv*16 + quad*4 + r;
            bool rst = (segpos[c*RCH + grow] == 0);
#pragma unroll
            for (int ct = 0; ct < 2; ct++) {
                float zx = ax[ct][r] + bxv[ct];
                float za = aa[ct][r] + bav[ct];
                float gx = __builtin_amdgcn_rcpf(1.f + __expf(-zx));
                float ga = __builtin_amdgcn_rcpf(1.f + __expf(-za));
                float av = __expf(-ga * ccv[ct]);
                float mult = __builtin_amdgcn_sqrtf(fmaf(-av, av, 1.f)); // sqrt(1-a^2)
                if (rst) { av = 0.f; mult = 1.f; }
                A_s[grow*33 + ct*16 + l16] = av;
                G_s[grow*33 + ct*16 + l16] = gx * mult;
            }
        }
        __syncthreads();                                   // B1

        // ---- phase B: per-seg scan, 32 cols x 16 segs of 8 rows
        const int col2 = tid & 31, seg = tid >> 5;
        float Pl[8], hl[8];
        float A = 1.f, hv = 0.f;
#pragma unroll
        for (int r = 0; r < 8; r++) {
            int grow = seg*8 + r;
            float a  = A_s[grow*33 + col2];
            float xn = G_s[grow*33 + col2] * X_s[grow*36 + col2];
            hv = fmaf(a, hv, xn); A *= a;
            Pl[r] = A; hl[r] = hv;
        }
        sgA[tid] = A; sgH[tid] = hv;                       // tid == seg*32+col2
        __syncthreads();                                   // B2

        // ---- phase C: seg prefix + apply + store
        float h0 = hc[c & 1][col2];
#pragma unroll
        for (int sp = 0; sp < 15; sp++)
            if (sp < seg) h0 = fmaf(sgA[sp*32 + col2], h0, sgH[sp*32 + col2]);

        float* yp = out + ((size_t)b*Lq + c*RCH + seg*8)*Wq + wcol0 + col2;
#pragma unroll
        for (int r = 0; r < 8; r++)
            yp[(size_t)r*Wq] = fmaf(Pl[r], h0, hl[r]);

        if (seg == 15) hc[(c+1) & 1][col2] = fmaf(Pl[7], h0, hl[7]);  // next carry
    }
    __syncthreads();
    if (tid < 32) out[(size_t)Mq*Wq + b*Wq + wcol0 + tid] = hc[NCH & 1][tid];  // last_h
}

extern "C" void kernel_launch(void* const* d_in, const int* in_sizes, int n_in,
                              void* d_out, int out_size, void* d_ws, size_t ws_size,
                              hipStream_t stream) {
    const float* x       = (const float*)d_in[0];
    const int*   segpos  = (const int*)  d_in[1];
    const float* prev_h  = (const float*)d_in[2];
    const float* ig_w    = (const float*)d_in[3];
    const float* ig_b    = (const float*)d_in[4];
    const float* ag_w    = (const float*)d_in[5];
    const float* ag_b    = (const float*)d_in[6];
    const float* a_param = (const float*)d_in[7];
    float* out = (float*)d_out;                    // [M*W] y then [B*W] last_h

    char* ws = (char*)d_ws;
    bf16*   wt    = (bf16*)  (ws + WS_WT);
    float*  c_arr = (float*) (ws + WS_C);

    prep2<<<256, 256, 0, stream>>>(ig_w, ag_w, a_param, wt, c_arr);
    rglru_fused<<<256, 512, 0, stream>>>(x, segpos, prev_h, wt, ig_b, ag_b, c_arr, out);
}

// Round 4
// 366.455 us; speedup vs baseline: 1.2317x; 1.2317x over previous
//
#include <hip/hip_runtime.h>
#include <hip/hip_bf16.h>
#include <cmath>

// Problem constants
#define Bq   4
#define Lq   4096
#define Wq   2048
#define Hq   8
#define Mq   (Bq*Lq)        // 16384 rows
#define RCH  128            // rows per chunk (8 waves x 16 rows)
#define NCH  (Lq/RCH)       // 32 chunks per sequence

typedef __bf16 bf16;
typedef __attribute__((ext_vector_type(8))) __bf16 bf16x8;
typedef __attribute__((ext_vector_type(4))) float  f32x4;

// ---- workspace layout (bytes) ----
#define WS_WT    0                               // bf16 [2][8][256][256] = 2 MiB (n-major)
#define WS_C     (2*8*256*256*2)                 // float [2048]

// ---------------- K0: weight transpose/cast (LDS tiled) + c vector ----------------
__global__ __launch_bounds__(256) void prep2(const float* __restrict__ ig_w,
                                             const float* __restrict__ ag_w,
                                             const float* __restrict__ a_param,
                                             bf16* __restrict__ wt, float* __restrict__ c_arr) {
    __shared__ float t[64*65];
    int bid = blockIdx.x;                 // 256 blocks: [g:1][h:3][nt:2][kt:2]
    int kt = bid & 3, nt = (bid >> 2) & 3, h = (bid >> 4) & 7, g = bid >> 7;
    const float* src = g ? ag_w : ig_w;
    int rr = threadIdx.x >> 6, cc = threadIdx.x & 63;
#pragma unroll
    for (int p = 0; p < 16; p++) {
        int kl = p*4 + rr;
        t[kl*65 + cc] = src[h*65536 + (kt*64 + kl)*256 + nt*64 + cc];  // coalesced read
    }
    if (bid < 8) {
        float ap = a_param[bid*256 + threadIdx.x];
        c_arr[bid*256 + threadIdx.x] = 8.0f * log1pf(__expf(ap));      // 8*softplus
    }
    __syncthreads();
#pragma unroll
    for (int p = 0; p < 16; p++) {
        int nl = p*4 + rr;
        wt[((size_t)((g*8 + h)*256) + nt*64 + nl)*256 + kt*64 + cc] = (bf16)t[cc*65 + nl]; // coalesced write
    }
}

// ---------------- K1: fused persistent-chain RG-LRU (8-wave, weights in LDS) -------
// 256 blocks = (stripe s:8)*(b:4)*(h:8), bid = s*32 + b*8 + h  -> bid%8==h: the 8
// stripe-blocks of an (b,h) x-slab land on one XCD (round-robin) for L2 reuse.
// Each block owns 32 channels of one batch, walks 32 chunks of 128 rows.
// Per chunk (ONE barrier):
//   A: MFMA(xs regs x LDS weight frags) -> acc; issue next xs; gates in regs
//      (raw x for the scan comes from a prefetched gate-layout read, L2-hot);
//      issue next xg/segpos.
//   B: in-lane 4-row scan; 2-step Kogge-Stone over quads via __shfl; write wave
//      aggregate to sg[parity] (4KB, ping-pong).
//   BARRIER
//   C: 7-step cross-wave ladder from hc[parity] + sg[parity]; store y; wave 7
//      writes hc[!parity].
// Hazard audit (1 barrier valid): sg/hc are parity ping-ponged; a wave can only
// write parity p again after passing the NEXT barrier, and every wave's parity-p
// reads precede its next barrier arrival -> no overlap. Weight LDS is read-only
// after the init barrier.
__global__ __launch_bounds__(512, 1) void rglru_fused(
    const float* __restrict__ x, const int* __restrict__ segpos,
    const float* __restrict__ prev_h,
    const bf16* __restrict__ wt, const float* __restrict__ igb,
    const float* __restrict__ agb, const float* __restrict__ c_arr,
    float* __restrict__ out)
{
    __shared__ bf16x8 Wl[32*64];                 // [(g*2+ct)*8+ks][lane] frags, 32 KB
    __shared__ float sgA[2][8][32], sgH[2][8][32];
    __shared__ float hc[2][32];

    const int tid = threadIdx.x;
    const int bid = blockIdx.x;
    const int h = bid & 7, b = (bid >> 3) & 3, s = bid >> 5;
    const int lane = tid & 63, wv = tid >> 6;
    const int l16 = lane & 15, quad = lane >> 4;
    const int wcol0 = h*256 + s*32;              // global channel base of this block

    // ---- fill weight LDS in exact B-fragment order (one-time, 32 KB)
    for (int t = tid; t < 2048; t += 512) {
        int ln = t & 63, ks = (t >> 6) & 7, ct = (t >> 9) & 1, g = t >> 10;
        int n  = s*32 + ct*16 + (ln & 15);
        int k  = ks*32 + (ln >> 4)*8;
        Wl[t] = *(const bf16x8*)&wt[((size_t)((g*8 + h)*256 + n))*256 + k];
    }
    float bxv[2], bav[2], ccv[2];
#pragma unroll
    for (int ct = 0; ct < 2; ct++) {
        int wf = wcol0 + ct*16 + l16;
        bxv[ct] = igb[wf]; bav[ct] = agb[wf]; ccv[ct] = c_arr[wf];
    }
    if (tid < 32) hc[0][tid] = prev_h[b*Wq + wcol0 + tid];

    // fragment-layout x pointer: lane (l16,quad) -> row wv*16+l16, cols quad*8 (+ks*32)
    const float* xfrag = x + ((size_t)b*Lq + wv*16 + l16)*Wq + h*256 + quad*8;
    // gate-layout x pointer: lane (quad,l16) -> row wv*16+quad*4 (+r), col wcol0+l16 (+ct*16)
    const float* xgate = x + ((size_t)b*Lq + wv*16 + quad*4)*Wq + wcol0 + l16;
    const int*   spp   = segpos + wv*16 + quad*4;

    // ---- prologue: chunk-0 prefetch into registers
    float4 xs[16]; float xg[8]; int sp[4];
#pragma unroll
    for (int ks = 0; ks < 8; ks++) {
        xs[2*ks]   = *(const float4*)(xfrag + ks*32);
        xs[2*ks+1] = *(const float4*)(xfrag + ks*32 + 4);
    }
#pragma unroll
    for (int r = 0; r < 4; r++) {
        sp[r] = spp[r];
#pragma unroll
        for (int ct = 0; ct < 2; ct++)
            xg[r*2+ct] = xgate[(size_t)r*Wq + ct*16];
    }
    __syncthreads();

    for (int c = 0; c < NCH; ++c) {
        const int cur = c & 1, nxt = cur ^ 1;
        const int cn  = (c < NCH-1) ? c+1 : c;

        // ---- phase A: MFMA against LDS weight fragments
        f32x4 ax[2], aa[2];
#pragma unroll
        for (int j = 0; j < 2; j++) { ax[j] = (f32x4){0.f,0.f,0.f,0.f}; aa[j] = (f32x4){0.f,0.f,0.f,0.f}; }
#pragma unroll
        for (int ks = 0; ks < 8; ks++) {
            float4 u0 = xs[2*ks], u1 = xs[2*ks+1];
            bf16x8 af;
            af[0]=(bf16)u0.x; af[1]=(bf16)u0.y; af[2]=(bf16)u0.z; af[3]=(bf16)u0.w;
            af[4]=(bf16)u1.x; af[5]=(bf16)u1.y; af[6]=(bf16)u1.z; af[7]=(bf16)u1.w;
            bf16x8 w0 = Wl[(0*8+ks)*64 + lane];   // ig, ct=0
            bf16x8 w1 = Wl[(1*8+ks)*64 + lane];   // ig, ct=1
            bf16x8 w2 = Wl[(2*8+ks)*64 + lane];   // ag, ct=0
            bf16x8 w3 = Wl[(3*8+ks)*64 + lane];   // ag, ct=1
            ax[0] = __builtin_amdgcn_mfma_f32_16x16x32_bf16(af, w0, ax[0], 0,0,0);
            ax[1] = __builtin_amdgcn_mfma_f32_16x16x32_bf16(af, w1, ax[1], 0,0,0);
            aa[0] = __builtin_amdgcn_mfma_f32_16x16x32_bf16(af, w2, aa[0], 0,0,0);
            aa[1] = __builtin_amdgcn_mfma_f32_16x16x32_bf16(af, w3, aa[1], 0,0,0);
        }
        {   // issue next-chunk fragment loads (xs regs dead after the converts above)
            const float* xp = xfrag + (size_t)cn*RCH*Wq;
#pragma unroll
            for (int ks = 0; ks < 8; ks++) {
                xs[2*ks]   = *(const float4*)(xp + ks*32);
                xs[2*ks+1] = *(const float4*)(xp + ks*32 + 4);
            }
        }

        // ---- gates in registers (acc layout == gate layout: row quad*4+r, col ct*16+l16)
        float av[8], xn[8];
#pragma unroll
        for (int r = 0; r < 4; r++) {
            bool rst = (sp[r] == 0);
#pragma unroll
            for (int ct = 0; ct < 2; ct++) {
                float zx = ax[ct][r] + bxv[ct];
                float za = aa[ct][r] + bav[ct];
                float gx = __builtin_amdgcn_rcpf(1.f + __expf(-zx));
                float ga = __builtin_amdgcn_rcpf(1.f + __expf(-za));
                float a  = __expf(-ga * ccv[ct]);
                float mult = __builtin_amdgcn_sqrtf(fmaf(-a, a, 1.f)); // sqrt(1-a^2)
                if (rst) { a = 0.f; mult = 1.f; }
                av[r*2+ct] = a;
                xn[r*2+ct] = gx * mult * xg[r*2+ct];
            }
        }
        {   // issue next-chunk gate-side loads (xg/sp dead after gates)
            const float* xp = xgate + (size_t)cn*RCH*Wq;
#pragma unroll
            for (int r = 0; r < 4; r++) {
                sp[r] = spp[cn*RCH + r];
#pragma unroll
                for (int ct = 0; ct < 2; ct++)
                    xg[r*2+ct] = xp[(size_t)r*Wq + ct*16];
            }
        }

        // ---- phase B: in-register scan. 4 rows in-lane, Kogge-Stone over quads.
        float Pl[8], hl[8], Awv[2], Hwv[2];
#pragma unroll
        for (int ct = 0; ct < 2; ct++) {
            float A = 1.f, hv = 0.f;
#pragma unroll
            for (int r = 0; r < 4; r++) {
                hv = fmaf(av[r*2+ct], hv, xn[r*2+ct]);
                A *= av[r*2+ct];
                Pl[ct*4+r] = A; hl[ct*4+r] = hv;
            }
            // inclusive (A,H) scan over quad dim: compose(prev,cur) = (Ap*Ac, Ac*Hp+Hc)
            float Asc = A, Hsc = hv;
            float Apv = __shfl(Asc, (lane-16) & 63), Hpv = __shfl(Hsc, (lane-16) & 63);
            if (quad >= 1) { Hsc = fmaf(Asc, Hpv, Hsc); Asc *= Apv; }
            Apv = __shfl(Asc, (lane-32) & 63); Hpv = __shfl(Hsc, (lane-32) & 63);
            if (quad >= 2) { Hsc = fmaf(Asc, Hpv, Hsc); Asc *= Apv; }
            float Aex = __shfl(Asc, (lane-16) & 63), Hex = __shfl(Hsc, (lane-16) & 63); // exclusive
            if (quad == 0) { Aex = 1.f; Hex = 0.f; }
#pragma unroll
            for (int r = 0; r < 4; r++) {          // make rows wave-seg-relative
                hl[ct*4+r] = fmaf(Pl[ct*4+r], Hex, hl[ct*4+r]);
                Pl[ct*4+r] *= Aex;
            }
            Awv[ct] = Asc; Hwv[ct] = Hsc;          // wave-seg aggregate (valid at quad==3)
            if (quad == 3) { sgA[cur][wv][ct*16+l16] = Asc; sgH[cur][wv][ct*16+l16] = Hsc; }
        }
        __syncthreads();

        // ---- phase C: cross-wave ladder + apply + store
#pragma unroll
        for (int ct = 0; ct < 2; ct++) {
            int col = ct*16 + l16;
            float h0 = hc[cur][col];
#pragma unroll
            for (int w = 0; w < 7; w++)            // wave-uniform predicate: no divergence
                if (w < wv) h0 = fmaf(sgA[cur][w][col], h0, sgH[cur][w][col]);
            float* yp = out + ((size_t)b*Lq + (size_t)c*RCH + wv*16 + quad*4)*Wq + wcol0 + col;
#pragma unroll
            for (int r = 0; r < 4; r++)
                yp[(size_t)r*Wq] = fmaf(Pl[ct*4+r], h0, hl[ct*4+r]);
            if (wv == 7 && quad == 3)
                hc[nxt][col] = fmaf(Awv[ct], h0, Hwv[ct]);  // block carry for next chunk
        }
    }
    __syncthreads();
    if (tid < 32) out[(size_t)Mq*Wq + b*Wq + wcol0 + tid] = hc[NCH & 1][tid];  // last_h
}

extern "C" void kernel_launch(void* const* d_in, const int* in_sizes, int n_in,
                              void* d_out, int out_size, void* d_ws, size_t ws_size,
                              hipStream_t stream) {
    const float* x       = (const float*)d_in[0];
    const int*   segpos  = (const int*)  d_in[1];
    const float* prev_h  = (const float*)d_in[2];
    const float* ig_w    = (const float*)d_in[3];
    const float* ig_b    = (const float*)d_in[4];
    const float* ag_w    = (const float*)d_in[5];
    const float* ag_b    = (const float*)d_in[6];
    const float* a_param = (const float*)d_in[7];
    float* out = (float*)d_out;                    // [M*W] y then [B*W] last_h

    char* ws = (char*)d_ws;
    bf16*   wt    = (bf16*)  (ws + WS_WT);
    float*  c_arr = (float*) (ws + WS_C);

    prep2<<<256, 256, 0, stream>>>(ig_w, ag_w, a_param, wt, c_arr);
    rglru_fused<<<256, 512, 0, stream>>>(x, segpos, prev_h, wt, ig_b, ag_b, c_arr, out);
}